// Round 6
// baseline (2573.356 us; speedup 1.0000x reference)
//
#include <hip/hip_runtime.h>
#include <hip/hip_fp16.h>

#define B_ 256
#define T_ 512
#define I_ 156
#define H_ 128
#define L_ 32
#define G_ 512  // 4*H

typedef _Float16 half_t;
typedef _Float16 h2_t __attribute__((ext_vector_type(2)));
typedef _Float16 f16x8 __attribute__((ext_vector_type(8)));
typedef float f32x4 __attribute__((ext_vector_type(4)));

union U8 { uint4 u; h2_t h2[4]; };

__device__ __forceinline__ float fdot2(h2_t a, h2_t b, float c) {
#if __has_builtin(__builtin_amdgcn_fdot2)
  return __builtin_amdgcn_fdot2(a, b, c, false);
#else
  return c + (float)a[0] * (float)b[0] + (float)a[1] * (float)b[1];
#endif
}

__device__ __forceinline__ h2_t pk2(float a, float b) {
  h2_t r; r[0] = (half_t)a; r[1] = (half_t)b; return r;
}

__device__ __forceinline__ float sigf(float x) { return 1.0f / (1.0f + __expf(-x)); }
__device__ __forceinline__ float tanhf_(float x) {
  x = fminf(fmaxf(x, -20.f), 20.f);
  float e = __expf(2.f * x);
  return (e - 1.f) / (e + 1.f);
}

__device__ __forceinline__ f32x4 mfma16(f16x8 a, f16x8 b, f32x4 c) {
  return __builtin_amdgcn_mfma_f32_16x16x32_f16(a, b, c, 0, 0, 0);
}

// B-frag from row-major f32 W[rows][ld]; k >= kmax padded 0.
__device__ __forceinline__ f16x8 load_bfrag(const float* __restrict__ W, int row,
                                            int ld, int kbase, int kmax) {
  f16x8 r;
#pragma unroll
  for (int j = 0; j < 8; ++j) {
    int k = kbase + j;
    r[j] = (half_t)((k < kmax) ? W[(size_t)row * ld + k] : 0.f);
  }
  return r;
}

// ============ xproj: XP frag-order f16 = motion @ Wih^T + b ============
// grid 256 = 16 b16-blocks x 16 t-chunks(32).  512 thr (8 waves).
// Wave wv owns n-tiles wv*4..wv*4+3.  M-tile = 16 batches at one t.
__global__ __launch_bounds__(512, 2) void xproj_mfma(
    const float* __restrict__ motion, const float* __restrict__ Wih,
    const float* __restrict__ bv, half_t* __restrict__ XP)
{
  const int tid = threadIdx.x, lane = tid & 63, wv = tid >> 6;
  const int l15 = lane & 15, lg = lane >> 4;
  const int b16 = blockIdx.x >> 4;
  const int tc  = blockIdx.x & 15;

  __shared__ half_t xA[128 * 160];  // [row=tt*16+b][160 halfs], XOR-swizzled

  f16x8 fB[4][5];
  float bn[4];
#pragma unroll
  for (int i = 0; i < 4; ++i) {
    int n = (wv * 4 + i) * 16 + l15;
    bn[i] = bv[n];
#pragma unroll
    for (int kk = 0; kk < 5; ++kk)
      fB[i][kk] = load_bfrag(Wih, n, I_, kk * 32 + lg * 8, I_);
  }
  uint2* xout = (uint2*)XP;

  for (int sc = 0; sc < 4; ++sc) {
    const int t0 = tc * 32 + sc * 8;
    {
      int r = tid >> 2, q = tid & 3;        // r: 0..127 -> (tt,b)
      int tt = r >> 4, bb = r & 15;
      const float* src = motion + ((size_t)(b16 * 16 + bb) * T_ + (t0 + tt)) * I_;
#pragma unroll
      for (int i2 = 0; i2 < 10; ++i2) {
        int c4 = q * 10 + i2;               // 4-half slot, 0..39
        h2_t v0 = pk2(0.f, 0.f), v1 = pk2(0.f, 0.f);
        if (c4 < 39) {
          float4 m4 = *(const float4*)(src + c4 * 4);
          v0 = pk2(m4.x, m4.y); v1 = pk2(m4.z, m4.w);
        }
        int idx = (r * 160 + c4 * 4) ^ ((bb & 7) << 3);
        *(h2_t*)&xA[idx]     = v0;
        *(h2_t*)&xA[idx + 2] = v1;
      }
    }
    __syncthreads();
    for (int tt = 0; tt < 8; ++tt) {
      f16x8 fA[5];
#pragma unroll
      for (int kk = 0; kk < 5; ++kk) {
        int row = tt * 16 + l15;
        int idx = (row * 160 + kk * 32 + lg * 8) ^ ((l15 & 7) << 3);
        fA[kk] = *(const f16x8*)&xA[idx];
      }
      const int t = t0 + tt;
#pragma unroll
      for (int i = 0; i < 4; ++i) {
        f32x4 acc = {bn[i], bn[i], bn[i], bn[i]};
#pragma unroll
        for (int kk = 0; kk < 5; ++kk) acc = mfma16(fA[kk], fB[i][kk], acc);
        uint2 o; half_t* oh = (half_t*)&o;
#pragma unroll
        for (int r = 0; r < 4; ++r) oh[r] = (half_t)acc[r];
        xout[((size_t)(b16 * 32 + wv * 4 + i) * T_ + t) * 64 + lane] = o;
      }
    }
    __syncthreads();
  }
}

// ============ encoder recurrence, MFMA.  grid 16 x 512 thr ============
__global__ __launch_bounds__(512, 2) void enc_mfma(
    const half_t* __restrict__ XP, const float* __restrict__ Whh,
    const float* __restrict__ eps,
    const float* __restrict__ muW, const float* __restrict__ mub,
    const float* __restrict__ varW, const float* __restrict__ varb,
    const float* __restrict__ fcW, const float* __restrict__ fcb,
    float* __restrict__ dout, float* __restrict__ dh0g,
    float* __restrict__ accums)
{
  const int tid = threadIdx.x, lane = tid & 63, wv = tid >> 6;
  const int l15 = lane & 15, lg = lane >> 4;
  const int b16 = blockIdx.x;

  __shared__ half_t hA[2048];     // h[16][128] f16 swizzled
  __shared__ float  gl[8192];     // gates [512][16] f32 swizzled
  __shared__ float  hf[2048];     // final h f32 (tail)
  __shared__ float  mulv[1024];
  __shared__ float  zs[512];
  __shared__ float  red[8];

  f16x8 fB[4][4];
#pragma unroll
  for (int i = 0; i < 4; ++i) {
    int n = (wv * 4 + i) * 16 + l15;
#pragma unroll
    for (int kk = 0; kk < 4; ++kk)
      fB[i][kk] = load_bfrag(Whh, n, H_, kk * 32 + lg * 8, H_);
  }

  ((uint2*)hA)[tid] = make_uint2(0u, 0u);  // h0 = 0
  float cc[4] = {0.f, 0.f, 0.f, 0.f};
  float hr[4] = {0.f, 0.f, 0.f, 0.f};

  const uint2* xptr = (const uint2*)XP;
  int xbase[4];
#pragma unroll
  for (int i = 0; i < 4; ++i)
    xbase[i] = ((b16 * 32 + wv * 4 + i) * T_) * 64 + lane;
  uint2 xpv[2][4];
#pragma unroll
  for (int i = 0; i < 4; ++i) {
    xpv[0][i] = xptr[xbase[i]];
    xpv[1][i] = xptr[xbase[i] + 64];
  }

  const int m_c = tid >> 7;   // cell: m base (0..3), pairs m_c+4p
  const int h_c = tid & 127;

  __syncthreads();

  for (int t = 0; t < T_; ++t) {
    const int cur = t & 1;
    f16x8 fA[4];
#pragma unroll
    for (int kk = 0; kk < 4; ++kk) {
      int idx = (l15 * 128 + kk * 32 + lg * 8) ^ ((l15 & 7) << 3);
      fA[kk] = *(const f16x8*)&hA[idx];
    }
#pragma unroll
    for (int i = 0; i < 4; ++i) {
      const half_t* xh = (const half_t*)&xpv[cur][i];
      f32x4 acc;
#pragma unroll
      for (int r = 0; r < 4; ++r) acc[r] = (float)xh[r];
#pragma unroll
      for (int kk = 0; kk < 4; ++kk) acc = mfma16(fA[kk], fB[i][kk], acc);
      int n = (wv * 4 + i) * 16 + l15;
      int gidx = (n * 16 + lg * 4) ^ ((n & 7) << 2);
      *(f32x4*)&gl[gidx] = acc;
    }
    if (t + 2 < T_) {
#pragma unroll
      for (int i = 0; i < 4; ++i)
        xpv[cur][i] = xptr[xbase[i] + (t + 2) * 64];
    }
    asm volatile("s_waitcnt lgkmcnt(0)" ::: "memory");
    __builtin_amdgcn_s_barrier();
    __builtin_amdgcn_sched_barrier(0);
#pragma unroll
    for (int p = 0; p < 4; ++p) {
      int m = m_c + p * 4;
      int sw = (h_c & 7) << 2;
      float ig = gl[(h_c * 16 + m) ^ sw];
      float fg = gl[((h_c + 128) * 16 + m) ^ sw];
      float gg = gl[((h_c + 256) * 16 + m) ^ sw];
      float og = gl[((h_c + 384) * 16 + m) ^ sw];
      float c2 = sigf(fg) * cc[p] + sigf(ig) * tanhf_(gg);
      cc[p] = c2;
      float hv = sigf(og) * tanhf_(c2);
      hr[p] = hv;
      hA[(m * 128 + h_c) ^ ((m & 7) << 3)] = (half_t)hv;
    }
    asm volatile("s_waitcnt lgkmcnt(0)" ::: "memory");
    __builtin_amdgcn_s_barrier();
    __builtin_amdgcn_sched_barrier(0);
  }

  // ---- tail ----
#pragma unroll
  for (int p = 0; p < 4; ++p) hf[(m_c + p * 4) * 128 + h_c] = hr[p];
  __syncthreads();
  {
    int b = tid >> 5, oo = tid & 31;
    const float* h0 = &hf[b * 128];
    float am = mub[oo], av = varb[oo];
    const float* wm = &muW[oo * H_];
    const float* wvv = &varW[oo * H_];
    for (int k = 0; k < H_; ++k) { float hv = h0[k]; am += wm[k] * hv; av += wvv[k] * hv; }
    mulv[b * 64 + oo] = am;
    mulv[b * 64 + 32 + oo] = av;
    int bg = b16 * 16 + b;
    dout[(size_t)B_ * T_ * I_ + bg * L_ + oo] = am;
    dout[(size_t)B_ * T_ * I_ + B_ * L_ + bg * L_ + oo] = av;
  }
  __syncthreads();
  float kt;
  {
    int b = tid >> 5, l = tid & 31;
    float mu = mulv[b * 64 + l], lv = mulv[b * 64 + 32 + l];
    int bg = b16 * 16 + b;
    float z = mu + eps[bg * L_ + l] * __expf(0.5f * lv);
    zs[b * 32 + l] = z;
    kt = 1.f + lv - mu * mu - __expf(lv);
  }
#pragma unroll
  for (int off = 32; off > 0; off >>= 1) kt += __shfl_down(kt, off, 64);
  if (lane == 0) red[wv] = kt;
  __syncthreads();
  if (tid == 0) {
    float s = 0.f;
#pragma unroll
    for (int w = 0; w < 8; ++w) s += red[w];
    atomicAdd(&accums[1], s);
  }
  {
    int b = tid >> 5, hb = (tid & 31) * 4;
    int bg = b16 * 16 + b;
#pragma unroll
    for (int q = 0; q < 4; ++q) {
      int hh = hb + q;
      float a = fcb[hh];
      const float* wr = &fcW[hh * L_];
#pragma unroll
      for (int l = 0; l < L_; ++l) a += wr[l] * zs[b * 32 + l];
      dh0g[(size_t)bg * H_ + hh] = a;
    }
  }
}

// ============ decoder recurrence, MFMA.  grid 16 x 512 thr ============
__global__ __launch_bounds__(512, 2) void dec_mfma(
    const float* __restrict__ Wih, const float* __restrict__ Whh,
    const float* __restrict__ bv, const float* __restrict__ dh0g,
    half_t* __restrict__ hist)
{
  const int tid = threadIdx.x, lane = tid & 63, wv = tid >> 6;
  const int l15 = lane & 15, lg = lane >> 4;
  const int b16 = blockIdx.x;

  __shared__ half_t hA[2048];
  __shared__ float  gl[8192];

  f16x8 fB[4][4];
  float bn[4];
#pragma unroll
  for (int i = 0; i < 4; ++i) {
    int n = (wv * 4 + i) * 16 + l15;
    bn[i] = bv[n];
#pragma unroll
    for (int kk = 0; kk < 4; ++kk) {
      f16x8 r;
#pragma unroll
      for (int j = 0; j < 8; ++j) {
        int k = kk * 32 + lg * 8 + j;
        r[j] = (half_t)(Wih[(size_t)n * H_ + k] + Whh[(size_t)n * H_ + k]);
      }
      fB[i][kk] = r;
    }
  }

  const int m_c = tid >> 7;
  const int h_c = tid & 127;

  float cc[4] = {0.f, 0.f, 0.f, 0.f};
  half_t* hp[4];
#pragma unroll
  for (int p = 0; p < 4; ++p) {
    int m = m_c + p * 4;
    float h0 = dh0g[(size_t)(b16 * 16 + m) * H_ + h_c];
    hA[(m * 128 + h_c) ^ ((m & 7) << 3)] = (half_t)h0;
    hp[p] = hist + ((size_t)(b16 * 16 + m) * T_) * H_ + h_c;
  }
  __syncthreads();

  for (int t = 0; t < T_; ++t) {
    f16x8 fA[4];
#pragma unroll
    for (int kk = 0; kk < 4; ++kk) {
      int idx = (l15 * 128 + kk * 32 + lg * 8) ^ ((l15 & 7) << 3);
      fA[kk] = *(const f16x8*)&hA[idx];
    }
#pragma unroll
    for (int i = 0; i < 4; ++i) {
      f32x4 acc = {bn[i], bn[i], bn[i], bn[i]};
#pragma unroll
      for (int kk = 0; kk < 4; ++kk) acc = mfma16(fA[kk], fB[i][kk], acc);
      int n = (wv * 4 + i) * 16 + l15;
      int gidx = (n * 16 + lg * 4) ^ ((n & 7) << 2);
      *(f32x4*)&gl[gidx] = acc;
    }
    asm volatile("s_waitcnt lgkmcnt(0)" ::: "memory");
    __builtin_amdgcn_s_barrier();
    __builtin_amdgcn_sched_barrier(0);
#pragma unroll
    for (int p = 0; p < 4; ++p) {
      int m = m_c + p * 4;
      int sw = (h_c & 7) << 2;
      float ig = gl[(h_c * 16 + m) ^ sw];
      float fg = gl[((h_c + 128) * 16 + m) ^ sw];
      float gg = gl[((h_c + 256) * 16 + m) ^ sw];
      float og = gl[((h_c + 384) * 16 + m) ^ sw];
      float c2 = sigf(fg) * cc[p] + sigf(ig) * tanhf_(gg);
      cc[p] = c2;
      float hv = sigf(og) * tanhf_(c2);
      half_t hvh = (half_t)hv;
      hA[(m * 128 + h_c) ^ ((m & 7) << 3)] = hvh;
      hp[p][t * H_] = hvh;             // h history (fire-and-forget)
    }
    asm volatile("s_waitcnt lgkmcnt(0)" ::: "memory");
    __builtin_amdgcn_s_barrier();
    __builtin_amdgcn_sched_barrier(0);
  }
}

// ============ proj: recon = hist @ oW^T + b, fused rec-loss ============
// grid 1024 x 512 thr: 128 hist rows per block.
__global__ __launch_bounds__(512, 2) void proj_mfma(
    const half_t* __restrict__ hist, const float* __restrict__ oW,
    const float* __restrict__ ob, const float* __restrict__ motion,
    float* __restrict__ recon, float* __restrict__ accums)
{
  const int tid = threadIdx.x, lane = tid & 63, wv = tid >> 6;
  const int l15 = lane & 15, lg = lane >> 4;
  const int R0 = blockIdx.x * 128;

  __shared__ half_t xA[128 * 128];
  __shared__ float red[8];

  {
    const uint4* src = (const uint4*)(hist + (size_t)R0 * H_);
#pragma unroll
    for (int q = 0; q < 4; ++q) {
      int u = tid + q * 512;
      int row = u >> 4, ccu = u & 15;
      uint4 v = src[u];
      int idx = (row * 128 + ccu * 8) ^ ((row & 7) << 3);
      *(uint4*)&xA[idx] = v;
    }
  }
  const int nt = (wv < 2) ? 2 : 1;
  f16x8 fB[2][4];
  float bn[2];
  int   nn[2];
#pragma unroll
  for (int s = 0; s < 2; ++s) {
    int tile = (s == 0) ? wv : wv + 8;
    int n = tile * 16 + l15;
    nn[s] = n;
    bool valid = (s < nt) && (n < I_);
    bn[s] = valid ? ob[n] : 0.f;
#pragma unroll
    for (int kk = 0; kk < 4; ++kk) {
      f16x8 r;
      if (valid) r = load_bfrag(oW, n, H_, kk * 32 + lg * 8, H_);
      else {
#pragma unroll
        for (int j = 0; j < 8; ++j) r[j] = (half_t)0.f;
      }
      fB[s][kk] = r;
    }
  }
  __syncthreads();

  float rl = 0.f;
  for (int mt = 0; mt < 8; ++mt) {
    f16x8 fA[4];
#pragma unroll
    for (int kk = 0; kk < 4; ++kk) {
      int idx = ((mt * 16 + l15) * 128 + kk * 32 + lg * 8) ^ ((l15 & 7) << 3);
      fA[kk] = *(const f16x8*)&xA[idx];
    }
#pragma unroll
    for (int s = 0; s < 2; ++s) {
      if (s >= nt) break;
      f32x4 acc = {bn[s], bn[s], bn[s], bn[s]};
#pragma unroll
      for (int kk = 0; kk < 4; ++kk) acc = mfma16(fA[kk], fB[s][kk], acc);
      int n = nn[s];
      if (n < I_) {
#pragma unroll
        for (int r = 0; r < 4; ++r) {
          size_t grow = (size_t)R0 + mt * 16 + lg * 4 + r;
          size_t a = grow * I_ + n;
          float v = acc[r];
          recon[a] = v;
          float d = v - motion[a];
          rl += d * d;
        }
      }
    }
  }
#pragma unroll
  for (int off = 32; off > 0; off >>= 1) rl += __shfl_down(rl, off, 64);
  if (lane == 0) red[wv] = rl;
  __syncthreads();
  if (tid == 0) {
    float s = 0.f;
#pragma unroll
    for (int w = 0; w < 8; ++w) s += red[w];
    atomicAdd(&accums[0], s);
  }
}

// ================= fallback vector path (R2-proven) =================
__global__ __launch_bounds__(1024) void enc_fb_kernel(
    const float* __restrict__ motion, const float* __restrict__ eps,
    const float* __restrict__ Wih, const float* __restrict__ Whh,
    const float* __restrict__ bv,
    const float* __restrict__ muW, const float* __restrict__ mub,
    const float* __restrict__ varW, const float* __restrict__ varb,
    const float* __restrict__ fcW, const float* __restrict__ fcb,
    float* __restrict__ dout, float* __restrict__ dh0,
    float* __restrict__ accums)
{
  const int tid  = threadIdx.x;
  const int part = tid >> 9;
  const int j    = tid & 511;
  const int b    = blockIdx.x;

  __shared__ h2_t xs[2][80];
  __shared__ h2_t hs[64];
  __shared__ float gl2[2][G_];
  __shared__ float hfv[H_];
  __shared__ float mulv[64];
  __shared__ float zsv[L_];

  h2_t wih[40];
  h2_t whh[32];
  {
    const int cbase = part * 80;
    const float* wr = Wih + (size_t)j * I_;
#pragma unroll
    for (int k = 0; k < 40; ++k) {
      int c0 = cbase + 2 * k;
      float a = (c0     < I_) ? wr[c0]     : 0.f;
      float c = (c0 + 1 < I_) ? wr[c0 + 1] : 0.f;
      wih[k] = pk2(a, c);
    }
    const float2* r2 = (const float2*)(Whh + (size_t)j * H_ + part * 64);
#pragma unroll
    for (int k = 0; k < 32; ++k) { float2 w = r2[k]; whh[k] = pk2(w.x, w.y); }
  }
  float cb0 = 0.f, cb1 = 0.f, cb2 = 0.f, cb3 = 0.f;
  if (tid < H_) {
    cb0 = bv[tid]; cb1 = bv[tid + H_]; cb2 = bv[tid + 2*H_]; cb3 = bv[tid + 3*H_];
  }
  float creg = 0.f, hreg = 0.f;
  if (tid < 64) hs[tid] = pk2(0.f, 0.f);
  if (tid < 4)  xs[tid >> 1][78 + (tid & 1)] = pk2(0.f, 0.f);
  const float2* mrow = (const float2*)(motion + (size_t)b * T_ * I_);
  const bool loader = (part == 1) && (j < 78);
  if (loader) { float2 m = mrow[j]; xs[0][j] = pk2(m.x, m.y); }
  __syncthreads();
  int cur = 0;
  float2 xreg;
  for (int t = 0; t < T_; ++t) {
    if (loader && t + 1 < T_) xreg = mrow[(t + 1) * 78 + j];
    float a0 = 0.f, a1 = 0.f, a2 = 0.f, a3 = 0.f;
    const U8* xv = (const U8*)&xs[cur][part * 40];
#pragma unroll
    for (int c = 0; c < 10; ++c) {
      U8 v = xv[c];
      a0 = fdot2(wih[4*c+0], v.h2[0], a0);
      a1 = fdot2(wih[4*c+1], v.h2[1], a1);
      a2 = fdot2(wih[4*c+2], v.h2[2], a2);
      a3 = fdot2(wih[4*c+3], v.h2[3], a3);
    }
    const U8* hv = (const U8*)&hs[part * 32];
#pragma unroll
    for (int c = 0; c < 8; ++c) {
      U8 v = hv[c];
      a0 = fdot2(whh[4*c+0], v.h2[0], a0);
      a1 = fdot2(whh[4*c+1], v.h2[1], a1);
      a2 = fdot2(whh[4*c+2], v.h2[2], a2);
      a3 = fdot2(whh[4*c+3], v.h2[3], a3);
    }
    gl2[part][j] = (a0 + a1) + (a2 + a3);
    if (loader && t + 1 < T_) xs[cur ^ 1][j] = pk2(xreg.x, xreg.y);
    __syncthreads();
    if (tid < H_) {
      float ig = gl2[0][tid]        + gl2[1][tid]        + cb0;
      float fg = gl2[0][tid +   H_] + gl2[1][tid +   H_] + cb1;
      float gg = gl2[0][tid + 2*H_] + gl2[1][tid + 2*H_] + cb2;
      float og = gl2[0][tid + 3*H_] + gl2[1][tid + 3*H_] + cb3;
      creg = sigf(fg) * creg + sigf(ig) * tanhf_(gg);
      hreg = sigf(og) * tanhf_(creg);
      ((half_t*)hs)[tid] = (half_t)hreg;
    }
    __syncthreads();
    cur ^= 1;
  }
  if (tid < H_) hfv[tid] = hreg;
  __syncthreads();
  if (tid < 64) {
    const float* wr = (tid < L_) ? (muW + tid * H_) : (varW + (tid - L_) * H_);
    float a = (tid < L_) ? mub[tid] : varb[tid - L_];
#pragma unroll 8
    for (int k = 0; k < H_; ++k) a += wr[k] * hfv[k];
    mulv[tid] = a;
    if (tid < L_) dout[(size_t)B_*T_*I_ + b * L_ + tid] = a;
    else          dout[(size_t)B_*T_*I_ + B_*L_ + b * L_ + (tid - L_)] = a;
  }
  __syncthreads();
  if (tid < L_) {
    float mu = mulv[tid], lv = mulv[tid + L_];
    float z = mu + eps[b * L_ + tid] * __expf(0.5f * lv);
    zsv[tid] = z;
    float kt = 1.f + lv - mu * mu - __expf(lv);
#pragma unroll
    for (int off = 16; off > 0; off >>= 1) kt += __shfl_down(kt, off, 64);
    if (tid == 0) atomicAdd(&accums[1], kt);
  }
  __syncthreads();
  if (tid < H_) {
    const float* wr = fcW + tid * L_;
    float a = fcb[tid];
#pragma unroll
    for (int l = 0; l < L_; ++l) a += wr[l] * zsv[l];
    dh0[b * H_ + tid] = a;
  }
}

__global__ __launch_bounds__(1024) void dec_fb_kernel(
    const float* __restrict__ motion,
    const float* __restrict__ Wih, const float* __restrict__ Whh,
    const float* __restrict__ bv,
    const float* __restrict__ oW, const float* __restrict__ ob,
    const float* __restrict__ dh0,
    float* __restrict__ dout, float* __restrict__ accums)
{
  const int tid  = threadIdx.x;
  const int part = tid >> 9;
  const int j    = tid & 511;
  const int b    = blockIdx.x;

  __shared__ h2_t hs[64];
  __shared__ float gl[G_];
  __shared__ float red[16];

  h2_t wv[64];
  float bj = 0.f;
  if (part == 0) {
    const float2* r1 = (const float2*)(Wih + (size_t)j * H_);
    const float2* r2 = (const float2*)(Whh + (size_t)j * H_);
#pragma unroll
    for (int k = 0; k < 64; ++k) {
      float2 a = r1[k], c = r2[k];
      wv[k] = pk2(a.x + c.x, a.y + c.y);
    }
    bj = bv[j];
  } else if (j < I_) {
    const float2* r = (const float2*)(oW + (size_t)j * H_);
#pragma unroll
    for (int k = 0; k < 64; ++k) { float2 w = r[k]; wv[k] = pk2(w.x, w.y); }
    bj = ob[j];
  }
  float creg = 0.f, hreg = 0.f;
  if (tid < H_) {
    hreg = dh0[b * H_ + tid];
    ((half_t*)hs)[tid] = (half_t)hreg;
  }
  __syncthreads();
  const float* mr = motion + (size_t)b * T_ * I_;
  float* rr = dout + (size_t)b * T_ * I_;
  float rl = 0.f;
  for (int t = 0; t < T_; ++t) {
    if (part == 0) {
      float a0 = 0.f, a1 = 0.f, a2 = 0.f, a3 = 0.f;
      const U8* hv = (const U8*)hs;
#pragma unroll
      for (int c = 0; c < 16; ++c) {
        U8 v = hv[c];
        a0 = fdot2(wv[4*c+0], v.h2[0], a0);
        a1 = fdot2(wv[4*c+1], v.h2[1], a1);
        a2 = fdot2(wv[4*c+2], v.h2[2], a2);
        a3 = fdot2(wv[4*c+3], v.h2[3], a3);
      }
      gl[j] = bj + (a0 + a1) + (a2 + a3);
    } else if (j < I_ && t > 0) {
      float a0 = 0.f, a1 = 0.f, a2 = 0.f, a3 = 0.f;
      const U8* hv = (const U8*)hs;
#pragma unroll
      for (int c = 0; c < 16; ++c) {
        U8 v = hv[c];
        a0 = fdot2(wv[4*c+0], v.h2[0], a0);
        a1 = fdot2(wv[4*c+1], v.h2[1], a1);
        a2 = fdot2(wv[4*c+2], v.h2[2], a2);
        a3 = fdot2(wv[4*c+3], v.h2[3], a3);
      }
      float r = bj + (a0 + a1) + (a2 + a3);
      rr[(t - 1) * I_ + j] = r;
      float d = r - mr[(t - 1) * I_ + j];
      rl += d * d;
    }
    __syncthreads();
    if (tid < H_) {
      float ig = gl[tid], fg = gl[tid + H_], gg = gl[tid + 2*H_], og = gl[tid + 3*H_];
      creg = sigf(fg) * creg + sigf(ig) * tanhf_(gg);
      hreg = sigf(og) * tanhf_(creg);
      ((half_t*)hs)[tid] = (half_t)hreg;
    }
    __syncthreads();
  }
  if (part == 1 && j < I_) {
    float a0 = 0.f, a1 = 0.f, a2 = 0.f, a3 = 0.f;
    const U8* hv = (const U8*)hs;
#pragma unroll
    for (int c = 0; c < 16; ++c) {
      U8 v = hv[c];
      a0 = fdot2(wv[4*c+0], v.h2[0], a0);
      a1 = fdot2(wv[4*c+1], v.h2[1], a1);
      a2 = fdot2(wv[4*c+2], v.h2[2], a2);
      a3 = fdot2(wv[4*c+3], v.h2[3], a3);
    }
    float r = bj + (a0 + a1) + (a2 + a3);
    rr[511 * I_ + j] = r;
    float d = r - mr[511 * I_ + j];
    rl += d * d;
  }
  float v = rl;
#pragma unroll
  for (int off = 32; off > 0; off >>= 1) v += __shfl_down(v, off, 64);
  if ((tid & 63) == 0) red[tid >> 6] = v;
  __syncthreads();
  if (tid == 0) {
    float s = 0.f;
#pragma unroll
    for (int w = 0; w < 16; ++w) s += red[w];
    atomicAdd(&accums[0], s);
  }
}

__global__ void init_kernel(float* accums) {
  if (threadIdx.x < 2) accums[threadIdx.x] = 0.f;
}

__global__ void fin_kernel(const float* __restrict__ accums, float* __restrict__ dout) {
  if (threadIdx.x == 0) {
    float rec = accums[0] / (float)((size_t)B_ * T_ * I_);
    float kl = -0.5f * accums[1];
    dout[(size_t)B_*T_*I_ + 2 * B_ * L_] = rec + kl;
  }
}

extern "C" void kernel_launch(void* const* d_in, const int* in_sizes, int n_in,
                              void* d_out, int out_size, void* d_ws, size_t ws_size,
                              hipStream_t stream) {
  const float* motion = (const float*)d_in[0];
  const float* eps    = (const float*)d_in[1];
  const float* eWih   = (const float*)d_in[2];
  const float* eWhh   = (const float*)d_in[3];
  const float* eb     = (const float*)d_in[4];
  const float* muW    = (const float*)d_in[5];
  const float* mub    = (const float*)d_in[6];
  const float* varW   = (const float*)d_in[7];
  const float* varb   = (const float*)d_in[8];
  const float* fcW    = (const float*)d_in[9];
  const float* fcb    = (const float*)d_in[10];
  const float* dWih   = (const float*)d_in[11];
  const float* dWhh   = (const float*)d_in[12];
  const float* db     = (const float*)d_in[13];
  const float* oW     = (const float*)d_in[14];
  const float* obv    = (const float*)d_in[15];
  float* out = (float*)d_out;

  float* accums = (float*)d_ws;
  float* dh0    = (float*)((char*)d_ws + 256);
  const size_t sh_off = 256 + 131072;
  const size_t need = sh_off + (size_t)64 * 512 * 512 * 8;  // XP: 134.2 MB
  const bool big = ws_size >= need;
  half_t* XP   = (half_t*)((char*)d_ws + sh_off);
  half_t* hist = XP;  // aliased: XP dead after enc_mfma

  hipLaunchKernelGGL(init_kernel, dim3(1), dim3(64), 0, stream, accums);
  if (big) {
    hipLaunchKernelGGL(xproj_mfma, dim3(256), dim3(512), 0, stream,
                       motion, eWih, eb, XP);
    hipLaunchKernelGGL(enc_mfma, dim3(16), dim3(512), 0, stream,
                       XP, eWhh, eps, muW, mub, varW, varb, fcW, fcb,
                       out, dh0, accums);
    hipLaunchKernelGGL(dec_mfma, dim3(16), dim3(512), 0, stream,
                       dWih, dWhh, db, dh0, hist);
    hipLaunchKernelGGL(proj_mfma, dim3(1024), dim3(512), 0, stream,
                       hist, oW, obv, motion, out, accums);
  } else {
    hipLaunchKernelGGL(enc_fb_kernel, dim3(B_), dim3(1024), 0, stream,
                       motion, eps, eWih, eWhh, eb, muW, mub, varW, varb, fcW, fcb,
                       out, dh0, accums);
    hipLaunchKernelGGL(dec_fb_kernel, dim3(B_), dim3(1024), 0, stream,
                       motion, dWih, dWhh, db, oW, obv, dh0, out, accums);
  }
  hipLaunchKernelGGL(fin_kernel, dim3(1), dim3(64), 0, stream, accums, out);
}